// Round 3
// baseline (496.687 us; speedup 1.0000x reference)
//
#include <hip/hip_runtime.h>
#include <cstdint>
#include <cstddef>

#define NUM_C 81
#define NUM_A 16384
#define A_TILE 128
#define TILE_ELEMS (A_TILE * NUM_C)      // 10368 floats
#define TILE_F4    (TILE_ELEMS / 4)      // 2592 float4 = 5*512 + 32

typedef float f32x4 __attribute__((ext_vector_type(4)));  // nt-store-compatible

__device__ __forceinline__ float ce_one(float x, float t) {
    // softplus(x) - t*x, stable, HW transcendentals (v_exp_f32 / v_log_f32)
    float sp = fmaxf(x, 0.f) + __logf(1.f + __expf(-fabsf(x)));
    return fmaf(-t, x, sp);
}

// Compute ce for one float4, nontemporal-store to out, LDS-atomicMax into the
// per-anchor max accumulator. ce >= 0 (t in [0,1]) so uint bit order == float
// order and 0 is the max-identity.
__device__ __forceinline__ void process4(int i, float4 x, float4 t,
                                         f32x4* __restrict__ o4,
                                         unsigned int* smax) {
    f32x4 c;
    c.x = ce_one(x.x, t.x);
    c.y = ce_one(x.y, t.y);
    c.z = ce_one(x.z, t.z);
    c.w = ce_one(x.w, t.w);
    // out is write-once, never re-read by the GPU: bypass L2/L3 so the 172 MB
    // write stream doesn't evict the input streams from Infinity Cache.
    __builtin_nontemporal_store(c, &o4[i]);

    const int e0 = 4 * i;
    const int a0 = e0 / NUM_C;          // magic-mul, no HW divide
    const int r0 = e0 - a0 * NUM_C;     // 0..80
    if (r0 <= NUM_C - 4) {
        // all 4 elements in anchor a0
        float m = fmaxf(fmaxf(c.x, c.y), fmaxf(c.z, c.w));
        atomicMax(&smax[a0], __float_as_uint(m));
    } else {
        // split across a0 / a0+1 (r0 in {78,79,80}); tile is anchor-aligned
        // (10368 = 128*81) so a0+1 <= 127 always.
        const float vv[4] = {c.x, c.y, c.z, c.w};
        const int n0 = NUM_C - r0;      // 1..3 elems belong to a0
        float m0 = vv[0];
        for (int k = 1; k < n0; ++k) m0 = fmaxf(m0, vv[k]);
        float m1 = vv[n0];
        for (int k = n0 + 1; k < 4; ++k) m1 = fmaxf(m1, vv[k]);
        atomicMax(&smax[a0],     __float_as_uint(m0));
        atomicMax(&smax[a0 + 1], __float_as_uint(m1));
    }
}

// Kernel 1: 128 anchors per 256-thread block. Explicitly software-pipelined:
// the next pair's 4 float4 loads are issued before the current pair is
// processed, so each wave keeps 4-6 loads in flight (round-1 version had 2,
// and was memory-latency-bound at 2.4 TB/s). __launch_bounds__(256,4) gives
// the allocator up to ~128 VGPRs without spilling; LDS is only 512 B.
__global__ __launch_bounds__(256, 4)
void ce_max_tile(const float* __restrict__ logits,
                 const float* __restrict__ target,
                 const int* __restrict__ depth,
                 float* __restrict__ out,
                 float* __restrict__ max_ce,
                 int n_anchors) {
    __shared__ unsigned int smax[A_TILE];   // 512 B

    const int tid = threadIdx.x;
    if (tid < A_TILE) smax[tid] = 0u;       // identity for max of non-negative
    __syncthreads();

    const int b = blockIdx.x;
    const size_t ebase = (size_t)b * TILE_ELEMS;
    const float4* lg4 = (const float4*)(logits + ebase);
    const float4* tg4 = (const float4*)(target + ebase);
    f32x4* o4 = (f32x4*)(out + ebase);

    // prologue: first pair in flight
    int i = tid;
    float4 xa = lg4[i],       ta = tg4[i];
    float4 xb = lg4[i + 256], tb = tg4[i + 256];

    // 2592 = 5*512 + 32: 5 full pairs per thread, then 32-thread tail
    for (int j = 0; j < 5; ++j) {
        const int inext = i + 512;
        float4 xc, tc, xd, td;
        if (j < 4) {                        // uniform branch
            xc = lg4[inext];       tc = tg4[inext];
            xd = lg4[inext + 256]; td = tg4[inext + 256];
        } else if (tid < 32) {              // prefetch tail element
            xc = lg4[2560 + tid];  tc = tg4[2560 + tid];
        }
        process4(i,       xa, ta, o4, smax);
        process4(i + 256, xb, tb, o4, smax);
        i = inext;
        xa = xc; ta = tc; xb = xd; tb = td;
    }
    if (tid < 32) process4(2560 + tid, xa, ta, o4, smax);

    __syncthreads();

    if (tid < A_TILE) {
        const int ga = b * A_TILE + tid;
        if (ga < n_anchors)
            max_ce[ga] = (depth[ga] != 0) ? 0.f : __uint_as_float(smax[tid]);
    }
}

// Kernel 2: one block per batch row. Bisection top-K select (zero atomics),
// stable tie-break in index order, then zero non-kept anchor rows.
// (Unchanged; ~15 us, and for this data distribution K = A-1 so the zero
// loop writes almost nothing -- the selection logic is what's needed.)
__global__ __launch_bounds__(256)
void select_zero_kernel(const float* __restrict__ max_ce,
                        const int* __restrict__ depth,
                        const int* __restrict__ negpos_ratio,
                        float* __restrict__ out) {
    __shared__ unsigned int u[NUM_A];    // 64 KB, swizzled uint4 layout
    __shared__ int red[4];
    __shared__ int wave_eq[4];

    const int b   = blockIdx.x;
    const int tid = threadIdx.x;
    const int lane = tid & 63;
    const int wid  = tid >> 6;
    const float* mrow = max_ce + (size_t)b * NUM_A;
    const int*   drow = depth  + (size_t)b * NUM_A;
    uint4* u4 = (uint4*)u;

    // Swizzle: logical uint4 index i stored at phys(i); keeps both strided
    // loads and per-thread contiguous chunk reads spread across banks.
    auto phys = [](int i) -> int {
        return (i & ~15) | (((i & 15) + (i >> 4)) & 15);
    };

    // ---- load row (coalesced) + count positives ----
    const uint4* m4 = (const uint4*)mrow;
    const int4*  d4 = (const int4*)drow;
    int pos = 0;
    for (int i = tid; i < NUM_A / 4; i += 256) {   // 16 iters
        uint4 v = m4[i];
        u4[phys(i)] = v;
        int4 dd = d4[i];
        pos += (dd.x > 0) + (dd.y > 0) + (dd.z > 0) + (dd.w > 0);
    }
    #pragma unroll
    for (int off = 32; off > 0; off >>= 1) pos += __shfl_down(pos, off, 64);
    if (lane == 0) red[wid] = pos;
    __syncthreads();
    const int num_pos = red[0] + red[1] + red[2] + red[3];

    int K = negpos_ratio[0] * num_pos;
    if (K > NUM_A - 1) K = NUM_A - 1;

    // ---- bisection: T = K-th largest bit pattern (all values >= 0) ----
    unsigned int T;
    int eq_quota;
    if (K <= 0) {
        T = 0xFFFFFFFFu;   // unattainable
        eq_quota = 0;
    } else {
        unsigned int p = 0;
        for (int bit = 31; bit >= 0; --bit) {
            unsigned int q = p | (1u << bit);
            int cnt = 0;
            #pragma unroll 4
            for (int j = 0; j < 16; ++j) {   // chunk-ordered (swizzled) reads
                uint4 v = u4[16 * tid + ((j + tid) & 15)];
                cnt += (v.x >= q) + (v.y >= q) + (v.z >= q) + (v.w >= q);
            }
            #pragma unroll
            for (int off = 32; off > 0; off >>= 1) cnt += __shfl_down(cnt, off, 64);
            __syncthreads();          // protect red[] from previous iter
            if (lane == 0) red[wid] = cnt;
            __syncthreads();
            int total = red[0] + red[1] + red[2] + red[3];
            if (total >= K) p = q;
        }
        T = p;

        // g = #{v > T}
        int gl = 0;
        #pragma unroll 4
        for (int j = 0; j < 16; ++j) {
            uint4 v = u4[16 * tid + ((j + tid) & 15)];
            gl += (v.x > T) + (v.y > T) + (v.z > T) + (v.w > T);
        }
        #pragma unroll
        for (int off = 32; off > 0; off >>= 1) gl += __shfl_down(gl, off, 64);
        __syncthreads();
        if (lane == 0) red[wid] = gl;
        __syncthreads();
        eq_quota = K - (red[0] + red[1] + red[2] + red[3]);
    }

    // ---- stable tie rank: exclusive prefix of (==T) counts, chunk order ----
    // thread t owns logical anchors [64t, 64t+64)
    int eqc = 0;
    #pragma unroll 4
    for (int j = 0; j < 16; ++j) {
        uint4 v = u4[16 * tid + ((j + tid) & 15)];
        eqc += (v.x == T) + (v.y == T) + (v.z == T) + (v.w == T);
    }
    int inc = eqc;
    #pragma unroll
    for (int off = 1; off < 64; off <<= 1) {
        int n = __shfl_up(inc, off, 64);
        if (lane >= off) inc += n;
    }
    if (lane == 63) wave_eq[wid] = inc;
    __syncthreads();
    int woff = 0;
    for (int w = 0; w < wid; ++w) woff += wave_eq[w];
    int eqr = woff + (inc - eqc);    // exclusive rank of my chunk's first tie

    // ---- zero rows not in (positives | selected negatives) ----
    float* orow = out + (size_t)b * NUM_A * NUM_C;
    const int base_a = tid * 64;
    for (int j = 0; j < 16; ++j) {   // logical order within chunk
        uint4 v = u4[16 * tid + ((j + tid) & 15)];
        unsigned int vv[4] = {v.x, v.y, v.z, v.w};
        #pragma unroll
        for (int e = 0; e < 4; ++e) {
            int aa = base_a + 4 * j + e;
            unsigned int x = vv[e];
            bool selneg = (x > T);
            if (x == T) { selneg = (eqr < eq_quota); eqr++; }
            bool keep = (drow[aa] > 0) || selneg;
            if (!keep) {
                float* p = orow + (size_t)aa * NUM_C;
                #pragma unroll 9
                for (int c = 0; c < NUM_C; ++c) p[c] = 0.f;
            }
        }
    }
}

extern "C" void kernel_launch(void* const* d_in, const int* in_sizes, int n_in,
                              void* d_out, int out_size, void* d_ws, size_t ws_size,
                              hipStream_t stream) {
    const float* logits = (const float*)d_in[0];
    const float* target = (const float*)d_in[1];
    const int*   depth  = (const int*)d_in[2];
    const int*   negpos = (const int*)d_in[3];
    float* out = (float*)d_out;
    float* max_ce = (float*)d_ws;            // B*A*4 = 2 MB scratch

    const int n_anchors = in_sizes[2];       // B*A = 524288
    const int B = n_anchors / NUM_A;         // 32

    int blocks1 = (n_anchors + A_TILE - 1) / A_TILE;   // 4096
    ce_max_tile<<<blocks1, 256, 0, stream>>>(logits, target, depth, out, max_ce, n_anchors);
    select_zero_kernel<<<B, 256, 0, stream>>>(max_ce, depth, negpos, out);
}

// Round 4
// 486.147 us; speedup vs baseline: 1.0217x; 1.0217x over previous
//
#include <hip/hip_runtime.h>
#include <cstdint>
#include <cstddef>

#define NUM_C 81
#define NUM_A 16384
#define A_TILE 128
#define TILE_ELEMS (A_TILE * NUM_C)      // 10368 floats
#define TILE_F4    (TILE_ELEMS / 4)      // 2592 float4 = 256*10 + 32

__device__ __forceinline__ float ce_one(float x, float t) {
    // softplus(x) - t*x, stable, HW transcendentals (v_exp_f32 / v_log_f32)
    float sp = fmaxf(x, 0.f) + __logf(1.f + __expf(-fabsf(x)));
    return fmaf(-t, x, sp);
}

// Compute ce for one float4, store to out, LDS-atomicMax into the per-anchor
// max accumulator. ce >= 0 (t in [0,1]) so uint bit order == float order and
// 0 is the max-identity.
__device__ __forceinline__ void process4(int i, float4 x, float4 t,
                                         float4* __restrict__ o4,
                                         unsigned int* smax) {
    float4 c;
    c.x = ce_one(x.x, t.x);
    c.y = ce_one(x.y, t.y);
    c.z = ce_one(x.z, t.z);
    c.w = ce_one(x.w, t.w);
    o4[i] = c;                           // plain store (nt regressed: round 3)

    const int e0 = 4 * i;
    const int a0 = e0 / NUM_C;          // magic-mul, no HW divide
    const int r0 = e0 - a0 * NUM_C;     // 0..80
    if (r0 <= NUM_C - 4) {
        // all 4 elements in anchor a0
        float m = fmaxf(fmaxf(c.x, c.y), fmaxf(c.z, c.w));
        atomicMax(&smax[a0], __float_as_uint(m));
    } else {
        // split across a0 / a0+1 (r0 in {78,79,80}); tile is anchor-aligned
        // (10368 = 128*81) so a0+1 <= 127 always.
        const float vv[4] = {c.x, c.y, c.z, c.w};
        const int n0 = NUM_C - r0;      // 1..3 elems belong to a0
        float m0 = vv[0];
        for (int k = 1; k < n0; ++k) m0 = fmaxf(m0, vv[k]);
        float m1 = vv[n0];
        for (int k = n0 + 1; k < 4; ++k) m1 = fmaxf(m1, vv[k]);
        atomicMax(&smax[a0],     __float_as_uint(m0));
        atomicMax(&smax[a0 + 1], __float_as_uint(m1));
    }
}

// Kernel 1: 128 anchors per 256-thread block. MLP experiment, done properly
// this time: ALL 20 global_load_dwordx4 (10 float4 pairs per thread) are
// issued in a branch-free fully-unrolled block with compile-time indices
// before any consumption, so each wave holds 20 loads in flight and the
// compiler cannot sink them into branches (round-3 failure mode). Tail (last
// 32 float4s) handled outside the unrolled region. No launch_bounds
// min-waves hint: let the allocator keep the ~80 payload VGPRs.
__global__ __launch_bounds__(256)
void ce_max_tile(const float* __restrict__ logits,
                 const float* __restrict__ target,
                 const int* __restrict__ depth,
                 float* __restrict__ out,
                 float* __restrict__ max_ce,
                 int n_anchors) {
    __shared__ unsigned int smax[A_TILE];   // 512 B

    const int tid = threadIdx.x;
    if (tid < A_TILE) smax[tid] = 0u;       // identity for max of non-negative
    __syncthreads();

    const int b = blockIdx.x;
    const size_t ebase = (size_t)b * TILE_ELEMS;
    const float4* lg4 = (const float4*)(logits + ebase);
    const float4* tg4 = (const float4*)(target + ebase);
    float4* o4 = (float4*)(out + ebase);

    // ---- issue phase: 20 loads in flight, static indices ----
    float4 X[10], T[10];
    #pragma unroll
    for (int u = 0; u < 10; ++u) {
        X[u] = lg4[tid + 256 * u];
        T[u] = tg4[tid + 256 * u];
    }
    // tail loads (threads 0..31) issued before the compute phase too
    float4 xt, tt;
    const bool has_tail = (tid < 32);
    if (has_tail) { xt = lg4[2560 + tid]; tt = tg4[2560 + tid]; }

    // ---- consume phase: progressive vmcnt waits, compute+store+atomic ----
    #pragma unroll
    for (int u = 0; u < 10; ++u)
        process4(tid + 256 * u, X[u], T[u], o4, smax);
    if (has_tail) process4(2560 + tid, xt, tt, o4, smax);

    __syncthreads();

    if (tid < A_TILE) {
        const int ga = b * A_TILE + tid;
        if (ga < n_anchors)
            max_ce[ga] = (depth[ga] != 0) ? 0.f : __uint_as_float(smax[tid]);
    }
}

// Kernel 2: one block per batch row. Bisection top-K select (zero atomics),
// stable tie-break in index order, then zero non-kept anchor rows.
// (Unchanged; ~20-30 us, and for this data distribution K = A-1 so the zero
// loop writes almost nothing -- the selection logic is what's needed.)
__global__ __launch_bounds__(256)
void select_zero_kernel(const float* __restrict__ max_ce,
                        const int* __restrict__ depth,
                        const int* __restrict__ negpos_ratio,
                        float* __restrict__ out) {
    __shared__ unsigned int u[NUM_A];    // 64 KB, swizzled uint4 layout
    __shared__ int red[4];
    __shared__ int wave_eq[4];

    const int b   = blockIdx.x;
    const int tid = threadIdx.x;
    const int lane = tid & 63;
    const int wid  = tid >> 6;
    const float* mrow = max_ce + (size_t)b * NUM_A;
    const int*   drow = depth  + (size_t)b * NUM_A;
    uint4* u4 = (uint4*)u;

    // Swizzle: logical uint4 index i stored at phys(i); keeps both strided
    // loads and per-thread contiguous chunk reads spread across banks.
    auto phys = [](int i) -> int {
        return (i & ~15) | (((i & 15) + (i >> 4)) & 15);
    };

    // ---- load row (coalesced) + count positives ----
    const uint4* m4 = (const uint4*)mrow;
    const int4*  d4 = (const int4*)drow;
    int pos = 0;
    for (int i = tid; i < NUM_A / 4; i += 256) {   // 16 iters
        uint4 v = m4[i];
        u4[phys(i)] = v;
        int4 dd = d4[i];
        pos += (dd.x > 0) + (dd.y > 0) + (dd.z > 0) + (dd.w > 0);
    }
    #pragma unroll
    for (int off = 32; off > 0; off >>= 1) pos += __shfl_down(pos, off, 64);
    if (lane == 0) red[wid] = pos;
    __syncthreads();
    const int num_pos = red[0] + red[1] + red[2] + red[3];

    int K = negpos_ratio[0] * num_pos;
    if (K > NUM_A - 1) K = NUM_A - 1;

    // ---- bisection: T = K-th largest bit pattern (all values >= 0) ----
    unsigned int T;
    int eq_quota;
    if (K <= 0) {
        T = 0xFFFFFFFFu;   // unattainable
        eq_quota = 0;
    } else {
        unsigned int p = 0;
        for (int bit = 31; bit >= 0; --bit) {
            unsigned int q = p | (1u << bit);
            int cnt = 0;
            #pragma unroll 4
            for (int j = 0; j < 16; ++j) {   // chunk-ordered (swizzled) reads
                uint4 v = u4[16 * tid + ((j + tid) & 15)];
                cnt += (v.x >= q) + (v.y >= q) + (v.z >= q) + (v.w >= q);
            }
            #pragma unroll
            for (int off = 32; off > 0; off >>= 1) cnt += __shfl_down(cnt, off, 64);
            __syncthreads();          // protect red[] from previous iter
            if (lane == 0) red[wid] = cnt;
            __syncthreads();
            int total = red[0] + red[1] + red[2] + red[3];
            if (total >= K) p = q;
        }
        T = p;

        // g = #{v > T}
        int gl = 0;
        #pragma unroll 4
        for (int j = 0; j < 16; ++j) {
            uint4 v = u4[16 * tid + ((j + tid) & 15)];
            gl += (v.x > T) + (v.y > T) + (v.z > T) + (v.w > T);
        }
        #pragma unroll
        for (int off = 32; off > 0; off >>= 1) gl += __shfl_down(gl, off, 64);
        __syncthreads();
        if (lane == 0) red[wid] = gl;
        __syncthreads();
        eq_quota = K - (red[0] + red[1] + red[2] + red[3]);
    }

    // ---- stable tie rank: exclusive prefix of (==T) counts, chunk order ----
    // thread t owns logical anchors [64t, 64t+64)
    int eqc = 0;
    #pragma unroll 4
    for (int j = 0; j < 16; ++j) {
        uint4 v = u4[16 * tid + ((j + tid) & 15)];
        eqc += (v.x == T) + (v.y == T) + (v.z == T) + (v.w == T);
    }
    int inc = eqc;
    #pragma unroll
    for (int off = 1; off < 64; off <<= 1) {
        int n = __shfl_up(inc, off, 64);
        if (lane >= off) inc += n;
    }
    if (lane == 63) wave_eq[wid] = inc;
    __syncthreads();
    int woff = 0;
    for (int w = 0; w < wid; ++w) woff += wave_eq[w];
    int eqr = woff + (inc - eqc);    // exclusive rank of my chunk's first tie

    // ---- zero rows not in (positives | selected negatives) ----
    float* orow = out + (size_t)b * NUM_A * NUM_C;
    const int base_a = tid * 64;
    for (int j = 0; j < 16; ++j) {   // logical order within chunk
        uint4 v = u4[16 * tid + ((j + tid) & 15)];
        unsigned int vv[4] = {v.x, v.y, v.z, v.w};
        #pragma unroll
        for (int e = 0; e < 4; ++e) {
            int aa = base_a + 4 * j + e;
            unsigned int x = vv[e];
            bool selneg = (x > T);
            if (x == T) { selneg = (eqr < eq_quota); eqr++; }
            bool keep = (drow[aa] > 0) || selneg;
            if (!keep) {
                float* p = orow + (size_t)aa * NUM_C;
                #pragma unroll 9
                for (int c = 0; c < NUM_C; ++c) p[c] = 0.f;
            }
        }
    }
}

extern "C" void kernel_launch(void* const* d_in, const int* in_sizes, int n_in,
                              void* d_out, int out_size, void* d_ws, size_t ws_size,
                              hipStream_t stream) {
    const float* logits = (const float*)d_in[0];
    const float* target = (const float*)d_in[1];
    const int*   depth  = (const int*)d_in[2];
    const int*   negpos = (const int*)d_in[3];
    float* out = (float*)d_out;
    float* max_ce = (float*)d_ws;            // B*A*4 = 2 MB scratch

    const int n_anchors = in_sizes[2];       // B*A = 524288
    const int B = n_anchors / NUM_A;         // 32

    int blocks1 = (n_anchors + A_TILE - 1) / A_TILE;   // 4096
    ce_max_tile<<<blocks1, 256, 0, stream>>>(logits, target, depth, out, max_ce, n_anchors);
    select_zero_kernel<<<B, 256, 0, stream>>>(max_ce, depth, negpos, out);
}